// Round 6
// baseline (190.079 us; speedup 1.0000x reference)
//
#include <hip/hip_runtime.h>
#include <stdint.h>

// Problem constants (match reference)
#define NV1 200000
#define NLM 50000
#define NTOT 250000        // NV1 + NLM
#define TLEN 600
#define UU 10
#define NNZV1 800000
#define NNZLM 200000
#define NELEM (TLEN * UU)  // 6000 poisson elements

typedef float f32x4 __attribute__((ext_vector_type(4)));
typedef float f32x2 __attribute__((ext_vector_type(2)));

// ---------------- threefry2x32 (bit-exact JAX implementation) ----------------
__device__ __forceinline__ void tf2x32(uint32_t k0, uint32_t k1,
                                       uint32_t c0, uint32_t c1,
                                       uint32_t& o0, uint32_t& o1) {
  const uint32_t ks2 = k0 ^ k1 ^ 0x1BD11BDAu;
  uint32_t x0 = c0 + k0;
  uint32_t x1 = c1 + k1;
#define TF_RND(r) { x0 += x1; x1 = (x1 << (r)) | (x1 >> (32 - (r))); x1 ^= x0; }
  TF_RND(13) TF_RND(15) TF_RND(26) TF_RND(6)
  x0 += k1;  x1 += ks2 + 1u;
  TF_RND(17) TF_RND(29) TF_RND(16) TF_RND(24)
  x0 += ks2; x1 += k0 + 2u;
  TF_RND(13) TF_RND(15) TF_RND(26) TF_RND(6)
  x0 += k0;  x1 += k1 + 3u;
  TF_RND(17) TF_RND(29) TF_RND(16) TF_RND(24)
  x0 += k1;  x1 += ks2 + 4u;
  TF_RND(13) TF_RND(15) TF_RND(26) TF_RND(6)
  x0 += ks2; x1 += k0 + 5u;
#undef TF_RND
  o0 = x0; o1 = x1;
}

// ---------------- fused: zero WT (blocks [0,ZB)) + Poisson spikes -----------
#define WZ4 (NTOT * UU / 4)          // 625,000 float4
#define ZB  ((WZ4 + 255) / 256)      // 2442 zero blocks
#define SB  ((NELEM + 255) / 256)    // 24 spike blocks
__global__ void __launch_bounds__(256) init_kernel(f32x4* __restrict__ W4,
                                                   float* __restrict__ spikes) {
  const int b = blockIdx.x;
  if (b < ZB) {
    const int i = b * 256 + threadIdx.x;
    if (i < WZ4) W4[i] = (f32x4)(0.f);
    return;
  }
  // Poisson spikes, JAX partitionable-threefry semantics (verified round 2)
  const int e = (b - ZB) * 256 + threadIdx.x;
  if (e >= NELEM) return;
  uint32_t r0 = 0u, r1 = 42u;   // threefry_seed(42) = (0, 42)
  float S = 0.0f;
  int result = 63;
  for (int iter = 0; iter < 64; ++iter) {
    uint32_t n0, n1, s0, s1;
    tf2x32(r0, r1, 0u, 0u, n0, n1);   // new rng = hash(rng, (0,0)) full pair
    tf2x32(r0, r1, 0u, 1u, s0, s1);   // subkey  = hash(rng, (0,1)) full pair
    r0 = n0; r1 = n1;
    uint32_t h0, h1;
    tf2x32(s0, s1, 0u, (uint32_t)e, h0, h1);
    const uint32_t bits = h0 ^ h1;    // 32-bit fold of 64-bit hash output
    const float u = __uint_as_float((bits >> 9) | 0x3f800000u) - 1.0f;
    S += logf(u);
    if (!(S > -1.0f)) { result = iter; break; }
  }
  spikes[e] = (float)result;
}

// ---------------- fused COO scatter-add into transposed WT (u x NTOT) -------
#define NNZTOT (NNZV1 + NNZLM)
__global__ void scatter_kernel(const float* __restrict__ w_v1,
                               const int* __restrict__ rows_v1,
                               const int* __restrict__ cols_v1,
                               const float* __restrict__ w_lm,
                               const int* __restrict__ rows_lm,
                               const int* __restrict__ cols_lm,
                               float* __restrict__ WT) {
  const int i = blockIdx.x * blockDim.x + threadIdx.x;
  if (i >= NNZTOT) return;
  if (i < NNZV1) {
    atomicAdd(&WT[(size_t)cols_v1[i] * NTOT + rows_v1[i]], w_v1[i]);
  } else {
    const int j = i - NNZV1;
    atomicAdd(&WT[(size_t)cols_lm[j] * NTOT + NV1 + rows_lm[j]], w_lm[j]);
  }
}

// ---------------- Main: out[t,n] = sum_u spikes[t,u] * WT[u,n] --------------
// TTILE=75 -> grid 245x8 = 1960 blocks; with 8 blocks/CU resident (forced via
// launch_bounds min-waves=8 -> <=64 VGPR) the whole grid fits one residency
// round: no straggler tail. Spike rows padded to 12 floats so each t reads
// LDS as b128+b128+b64 (3 ops instead of 10 scalar broadcasts).
#define TTILE 75
#define SROW 12
#define NT4 (NTOT / 4)        // 62500
__global__ void __launch_bounds__(256, 8) out_kernel(const float* __restrict__ WT,
                                                     const float* __restrict__ spikes,
                                                     float* __restrict__ out) {
  __shared__ float s[TTILE * SROW];
  const int t0 = blockIdx.y * TTILE;
  for (int i = threadIdx.x; i < TTILE * SROW; i += 256) {
    const int row = i / SROW, u = i - row * SROW;
    s[i] = (u < UU) ? spikes[(t0 + row) * UU + u] : 0.f;
  }
  __syncthreads();

  const int n4 = blockIdx.x * 256 + threadIdx.x;
  if (n4 >= NT4) return;
  const int n = n4 * 4;

  f32x4 w[UU];
#pragma unroll
  for (int u = 0; u < UU; ++u)
    w[u] = *reinterpret_cast<const f32x4*>(&WT[(size_t)u * NTOT + n]);

  float* op = &out[(size_t)t0 * NTOT + n];
  for (int t = 0; t < TTILE; ++t) {
    const f32x4 sA = *reinterpret_cast<const f32x4*>(&s[t * SROW]);
    const f32x4 sB = *reinterpret_cast<const f32x4*>(&s[t * SROW + 4]);
    const f32x2 sC = *reinterpret_cast<const f32x2*>(&s[t * SROW + 8]);
    f32x4 acc = sA.x * w[0];
    acc += sA.y * w[1];
    acc += sA.z * w[2];
    acc += sA.w * w[3];
    acc += sB.x * w[4];
    acc += sB.y * w[5];
    acc += sB.z * w[6];
    acc += sB.w * w[7];
    acc += sC.x * w[8];
    acc += sC.y * w[9];
    __builtin_nontemporal_store(acc, reinterpret_cast<f32x4*>(op));
    op += NTOT;
  }
}

extern "C" void kernel_launch(void* const* d_in, const int* in_sizes, int n_in,
                              void* d_out, int out_size, void* d_ws, size_t ws_size,
                              hipStream_t stream) {
  // Input order: inp, w_v1, rows_v1, cols_v1, w_lm, rows_lm, cols_lm
  const float* w_v1    = (const float*)d_in[1];
  const int*   rows_v1 = (const int*)d_in[2];
  const int*   cols_v1 = (const int*)d_in[3];
  const float* w_lm    = (const float*)d_in[4];
  const int*   rows_lm = (const int*)d_in[5];
  const int*   cols_lm = (const int*)d_in[6];
  float* out = (float*)d_out;

  // Workspace: WT (10 x 250000 f32 = 10 MB) then spikes (6000 f32)
  float* WT = (float*)d_ws;
  float* spikes = WT + (size_t)NTOT * UU;
  const size_t need = ((size_t)NTOT * UU + NELEM) * sizeof(float);
  if (ws_size < need) return;

  init_kernel<<<ZB + SB, 256, 0, stream>>>((f32x4*)WT, spikes);
  scatter_kernel<<<(NNZTOT + 255) / 256, 256, 0, stream>>>(w_v1, rows_v1, cols_v1,
                                                           w_lm, rows_lm, cols_lm, WT);
  dim3 grid((NT4 + 255) / 256, TLEN / TTILE);
  out_kernel<<<grid, 256, 0, stream>>>(WT, spikes, out);
}